// Round 9
// baseline (215.283 us; speedup 1.0000x reference)
//
#include <hip/hip_runtime.h>
#include <hip/hip_bf16.h>
#include <stdint.h>

// DeformableBlock: fused [offset-conv (MFMA) + meta + deformable conv (MFMA GEMM)]
// -> GroupNorm+ReLU.  B=4, CIN=COUT=256, H=W=64, 3x3, GN groups=32.
// Round 18: 3 -> 2 dispatches. R17 proved (total - k_conv) ~= 79 us is launch/
// dispatch overhead + ~15 us kernel work (4x small-kernel rework changed nothing).
// Fuse GN apply into k_conv via device-scope atomic spin-join (NOT cooperative
// launch -- R16 showed that kills the container; this is plain launches only):
//  - co-residency guaranteed: 512 blocks, 54.3KB LDS, 52 VGPR -> 2 blocks/CU
//    exactly covers the grid; every block reaches its counter increment.
//  - per-batch join (128 blocks each, batch lives on 2 XCDs via swizzle).
//  - GN applied to accumulators in registers; out written once post-GN;
//    k_gn_apply (dispatch + 33.6 MB round-trip) deleted.

typedef unsigned short u16;
typedef __bf16 bf16x8 __attribute__((ext_vector_type(8)));
typedef float f32x4_t __attribute__((ext_vector_type(4)));

#define HW 4096

__device__ __forceinline__ uint32_t f32_to_bf16_rne(float f) {
  uint32_t u = __builtin_bit_cast(uint32_t, f);
  return (u + 0x7FFFu + ((u >> 16) & 1u)) >> 16;
}
__device__ __forceinline__ float bf_lo(uint32_t u) {
  return __builtin_bit_cast(float, u << 16);
}
__device__ __forceinline__ float bf_hi(uint32_t u) {
  return __builtin_bit_cast(float, u & 0xFFFF0000u);
}
__device__ __forceinline__ uint32_t blend2(uint32_t a, uint32_t b, uint32_t c,
                                           uint32_t d, float4 mw) {
  float lo = mw.x * bf_lo(a) + mw.y * bf_lo(b) + mw.z * bf_lo(c) + mw.w * bf_lo(d);
  float hi = mw.x * bf_hi(a) + mw.y * bf_hi(b) + mw.z * bf_hi(c) + mw.w * bf_hi(d);
  return f32_to_bf16_rne(lo) | (f32_to_bf16_rne(hi) << 16);
}

// ---------------- Kernel PRE: transpose (64ch x 64px tiles) + weight prep ----------------
// 1024 blocks x 256 thr. Tails: warr/owm prep; block 0 zeroes part + join counters.
__global__ __launch_bounds__(256) void k_pre(const float* __restrict__ x,
                                             const float* __restrict__ wsrc,
                                             const float* __restrict__ ow,
                                             u16* __restrict__ xt,
                                             u16* __restrict__ warr,
                                             u16* __restrict__ owm,
                                             float* __restrict__ part) {
  __shared__ float tile[64][65];  // 16,640 B
  int bid = blockIdx.x;
  int tid = threadIdx.x;
  int bz = bid >> 8;
  int c0 = ((bid >> 6) & 3) * 64;
  int p0 = (bid & 63) * 64;

  {
    int ch = tid >> 4;
    int q4 = (tid & 15) * 4;
#pragma unroll
    for (int r = 0; r < 4; r++) {
      int c = r * 16 + ch;
      float4 v = *(const float4*)&x[((size_t)(bz * 256 + c0 + c)) * HW + p0 + q4];
      tile[c][q4 + 0] = v.x;
      tile[c][q4 + 1] = v.y;
      tile[c][q4 + 2] = v.z;
      tile[c][q4 + 3] = v.w;
    }
  }
  __syncthreads();
  {
    int chunk = tid & 7;
    int pxr = tid >> 3;
#pragma unroll
    for (int it = 0; it < 2; it++) {
      int px = it * 32 + pxr;
      int cb = chunk * 8;
      uint4 u;
      u.x = f32_to_bf16_rne(tile[cb + 0][px]) | (f32_to_bf16_rne(tile[cb + 1][px]) << 16);
      u.y = f32_to_bf16_rne(tile[cb + 2][px]) | (f32_to_bf16_rne(tile[cb + 3][px]) << 16);
      u.z = f32_to_bf16_rne(tile[cb + 4][px]) | (f32_to_bf16_rne(tile[cb + 5][px]) << 16);
      u.w = f32_to_bf16_rne(tile[cb + 6][px]) | (f32_to_bf16_rne(tile[cb + 7][px]) << 16);
      *(uint4*)&xt[((size_t)(bz * HW + p0 + px)) * 256 + c0 + cb] = u;
    }
  }

#pragma unroll
  for (int k = 0; k < 3; k++) {
    int i = k * 256 + tid;
    if (i < 576) {
      int e = bid * 576 + i;
      int kk = e & 7, m = (e >> 3) & 255, g = (e >> 11) & 7, kc = e >> 14;
      int cin = (kc & 3) * 64 + g * 8 + kk;
      warr[e] = (u16)f32_to_bf16_rne(wsrc[m * 2304 + cin * 9 + (kc >> 2)]);
    }
  }
  if (tid < 72) {
    int e = bid * 72 + tid;
    int kk = e & 7, m = (e >> 3) & 31, g = (e >> 8) & 7, kc = e >> 11;
    int cin = (kc & 3) * 64 + g * 8 + kk;
    float v = (m < 18) ? ow[m * 2304 + cin * 9 + (kc >> 2)] : 0.f;
    owm[e] = (u16)f32_to_bf16_rne(v);
  }
  if (bid == 0) {
    if (tid < 256) part[tid] = 0.f;      // 4b x 32g x {s,ss}
    if (tid < 4) ((int*)(part + 256))[tid] = 0;  // join counters
  }
}

// ---------------- Kernel C: offset-conv + meta + deformable GEMM + GN (spin-join) ----------------
// Block = (b, 32-px tile), 512 blocks x 512 threads (8 waves, M=32/wave).
// Phases A/meta/B identical to R15 (best measured). Epilogue: GN partial
// atomicAdds -> per-batch join -> stats -> GN+ReLU applied from registers ->
// single out store.
__global__ __launch_bounds__(512, 4) void k_conv(
    const u16* __restrict__ xt, const u16* __restrict__ warr,
    const u16* __restrict__ owm, const float* __restrict__ ob,
    const float* __restrict__ gamma, const float* __restrict__ beta,
    float* __restrict__ out, float* __restrict__ part, int* __restrict__ cnt) {
  __shared__ char smem[54272];
  u16* stage = (u16*)smem;                   // phase A: [w8][2112 u16] (33792 B)
  float* off_part = (float*)(smem + 33792);  // phase A: [w8][px32][20]  (20480 B)
  int4* ci_s = (int4*)smem;                  // meta/B:  [288]           (4608 B)
  float4* mw_s = (float4*)(smem + 4608);     // meta/B:  [288]           (4608 B)
  u16* b_s = (u16*)(smem + 9216);            // phase B: [2buf][2set][2sub][16oct][136 u16] (34816 B)

  int tid = threadIdx.x;
  int lane = tid & 63;
  int wm = tid >> 6;  // 0..7
  int wk = (blockIdx.x & 7) * 64 + (blockIdx.x >> 3);  // XCD swizzle
  int b = wk >> 7;
  int pt = wk & 127;
  int p0 = pt * 32;
  int yrow = p0 >> 6, xbase = p0 & 63;

  // ---- Phase A: offset conv; wave w handles kc-chunks w, w+8, w+16, ... ----
  {
    u16* st = stage + wm * 2112;
    int q = lane & 15, pq = lane >> 4;
    int oct = lane & 7, pxs = lane >> 3;
    f32x4_t a2[2][2] = {};
#pragma unroll 1
    for (int kc = wm; kc < 36; kc += 8) {
      int tap = kc >> 2, cc = kc & 3;
      int ky = tap / 3, kx = tap % 3;
      int yy = yrow + ky - 1;
      bool vy = (yy >= 0) && (yy < 64);
#pragma unroll
      for (int i = 0; i < 4; i++) {
        int px = i * 8 + pxs;
        int xx2 = xbase + px + kx - 1;
        uint4 v = make_uint4(0u, 0u, 0u, 0u);
        if (vy && xx2 >= 0 && xx2 < 64)
          v = *(const uint4*)&xt[(b * HW + yy * 64 + xx2) * 256 + cc * 64 + oct * 8];
        *(uint4*)&st[oct * 264 + px * 8] = v;
      }
#pragma unroll
      for (int ks = 0; ks < 2; ks++) {
        int g = ks * 4 + pq;
        const u16* ab = owm + kc * 2048 + g * 256;
#pragma unroll
        for (int s = 0; s < 2; s++) {
          bf16x8 bfr = *(bf16x8*)&st[g * 264 + (s * 16 + q) * 8];
#pragma unroll
          for (int im = 0; im < 2; im++) {
            bf16x8 af = *(const bf16x8*)&ab[(im * 16 + q) * 8];
            a2[s][im] = __builtin_amdgcn_mfma_f32_16x16x32_bf16(af, bfr, a2[s][im], 0, 0, 0);
          }
        }
      }
    }
#pragma unroll
    for (int s = 0; s < 2; s++)
#pragma unroll
      for (int im = 0; im < 2; im++)
#pragma unroll
        for (int r = 0; r < 4; r++) {
          int oc = im * 16 + pq * 4 + r;
          if (oc < 18) off_part[(wm * 32 + s * 16 + q) * 20 + oc] = a2[s][im][r];
        }
  }
  __syncthreads();
  // ---- meta: 288 = 9 taps x 32 px ----
  for (int it = tid; it < 288; it += 512) {
    int tap = it >> 5;
    int px = it & 31;
    float dy = ob[2 * tap], dx = ob[2 * tap + 1];
#pragma unroll
    for (int wv = 0; wv < 8; wv++) {
      dy += off_part[(wv * 32 + px) * 20 + 2 * tap];
      dx += off_part[(wv * 32 + px) * 20 + 2 * tap + 1];
    }
    int ky = tap / 3, kx = tap % 3;
    int p = p0 + px;
    int yq = p >> 6, xq = p & 63;
    float py = (float)(yq - 1 + ky) + dy;
    float pxx = (float)(xq - 1 + kx) + dx;
    float y0f = floorf(py), x0f = floorf(pxx);
    float ty = py - y0f, tx = pxx - x0f;
    int y0 = (int)y0f, x0 = (int)x0f;
    int y1 = y0 + 1, x1 = x0 + 1;
    float wy0 = 1.f - ty, wy1 = ty, wx0 = 1.f - tx, wx1 = tx;
    bool vy0 = (y0 >= 0) && (y0 < 64), vy1 = (y1 >= 0) && (y1 < 64);
    bool vx0 = (x0 >= 0) && (x0 < 64), vx1 = (x1 >= 0) && (x1 < 64);
    int cy0 = min(max(y0, 0), 63), cy1 = min(max(y1, 0), 63);
    int cx0 = min(max(x0, 0), 63), cx1 = min(max(x1, 0), 63);
    int base = b * HW;
    int4 ci;
    ci.x = (base + cy0 * 64 + cx0) * 256;
    ci.y = (base + cy0 * 64 + cx1) * 256;
    ci.z = (base + cy1 * 64 + cx0) * 256;
    ci.w = (base + cy1 * 64 + cx1) * 256;
    float4 mw;
    mw.x = wy0 * wx0 * ((vy0 && vx0) ? 1.f : 0.f);
    mw.y = wy0 * wx1 * ((vy0 && vx1) ? 1.f : 0.f);
    mw.z = wy1 * wx0 * ((vy1 && vx0) ? 1.f : 0.f);
    mw.w = wy1 * wx1 * ((vy1 && vx1) ? 1.f : 0.f);
    ci_s[it] = ci;
    mw_s[it] = mw;
  }
  __syncthreads();

  // ---- Phase B: deformable GEMM M=256, N=32; 9 taps, 1 barrier/tap ----
  int col = lane & 15;
  int pq = lane >> 4;
  f32x4_t acc[2][2] = {};  // [sub][im]
  {
    int oct8 = tid & 15;
    int pxg = tid >> 4;
    int sub = pxg >> 4;
    int pxw = pxg & 15;
    int e0 = oct8 * 8;

    int4 ci = ci_s[pxg];
    float4 mw = mw_s[pxg];
    uint4 A0 = *(const uint4*)&xt[ci.x + e0];
    uint4 A1 = *(const uint4*)&xt[ci.y + e0];
    uint4 A2 = *(const uint4*)&xt[ci.z + e0];
    uint4 A3 = *(const uint4*)&xt[ci.w + e0];
    uint4 G0 = *(const uint4*)&xt[ci.x + 128 + e0];
    uint4 G1 = *(const uint4*)&xt[ci.y + 128 + e0];
    uint4 G2 = *(const uint4*)&xt[ci.z + 128 + e0];
    uint4 G3 = *(const uint4*)&xt[ci.w + 128 + e0];

#pragma unroll 1
    for (int dp = 0; dp < 9; dp++) {
      u16* bb = b_s + (dp & 1) * 8704;
      {
        uint4 u;
        u.x = blend2(A0.x, A1.x, A2.x, A3.x, mw);
        u.y = blend2(A0.y, A1.y, A2.y, A3.y, mw);
        u.z = blend2(A0.z, A1.z, A2.z, A3.z, mw);
        u.w = blend2(A0.w, A1.w, A2.w, A3.w, mw);
        *(uint4*)&bb[sub * 2176 + oct8 * 136 + pxw * 8] = u;
      }
      {
        uint4 v;
        v.x = blend2(G0.x, G1.x, G2.x, G3.x, mw);
        v.y = blend2(G0.y, G1.y, G2.y, G3.y, mw);
        v.z = blend2(G0.z, G1.z, G2.z, G3.z, mw);
        v.w = blend2(G0.w, G1.w, G2.w, G3.w, mw);
        *(uint4*)&bb[4352 + sub * 2176 + oct8 * 136 + pxw * 8] = v;
      }
      __syncthreads();  // all gathers already consumed -> vmcnt drain is free
      if (dp < 8) {
        ci = ci_s[(dp + 1) * 32 + pxg];
        float4 mwn = mw_s[(dp + 1) * 32 + pxg];
        A0 = *(const uint4*)&xt[ci.x + e0];
        A1 = *(const uint4*)&xt[ci.y + e0];
        A2 = *(const uint4*)&xt[ci.z + e0];
        A3 = *(const uint4*)&xt[ci.w + e0];
        G0 = *(const uint4*)&xt[ci.x + 128 + e0];
        G1 = *(const uint4*)&xt[ci.y + 128 + e0];
        G2 = *(const uint4*)&xt[ci.z + 128 + e0];
        G3 = *(const uint4*)&xt[ci.w + 128 + e0];
        mw = mwn;
      }
      __builtin_amdgcn_s_setprio(1);
#pragma unroll
      for (int ks = 0; ks < 8; ks++) {
        int set = ks >> 2;
        int ro = (ks & 3) * 4 + pq;
        const u16* bp = bb + set * 4352 + ro * 136 + col * 8;
        bf16x8 bb0 = *(const bf16x8*)&bp[0];
        bf16x8 bb1 = *(const bf16x8*)&bp[2176];
        int kc = dp * 4 + (ks >> 1);
        int gg = (ks & 1) * 4 + pq;
        const u16* ab = warr + kc * 16384 + gg * 2048 + (wm * 32 + col) * 8;
#pragma unroll
        for (int im = 0; im < 2; im++) {
          bf16x8 af = *(const bf16x8*)&ab[im * 128];
          acc[0][im] = __builtin_amdgcn_mfma_f32_16x16x32_bf16(af, bb0, acc[0][im], 0, 0, 0);
          acc[1][im] = __builtin_amdgcn_mfma_f32_16x16x32_bf16(af, bb1, acc[1][im], 0, 0, 0);
        }
      }
      __builtin_amdgcn_s_setprio(0);
    }
  }

  // ---- GN partial sums from registers (no out store yet) ----
#pragma unroll
  for (int im = 0; im < 2; im++) {
    float s = 0.f, ss = 0.f;
#pragma unroll
    for (int sb = 0; sb < 2; sb++)
#pragma unroll
      for (int r = 0; r < 4; r++) {
        float v = acc[sb][im][r];
        s += v;
        ss += v * v;
      }
#pragma unroll
    for (int msk = 1; msk <= 16; msk <<= 1) {
      s += __shfl_xor(s, msk);
      ss += __shfl_xor(ss, msk);
    }
    if ((lane & 31) == 0) {
      int grp = wm * 4 + im * 2 + (lane >> 5);
      float* pp = part + (b * 32 + grp) * 2;
      atomicAdd(pp, s);
      atomicAdd(pp + 1, ss);
    }
  }

  // ---- per-batch join: all 128 blocks of batch b must land their partials ----
  __threadfence();   // make this block's atomicAdds visible device-wide
  __syncthreads();   // all threads' adds + fences done
  if (tid == 0) {
    __hip_atomic_fetch_add(&cnt[b], 1, __ATOMIC_ACQ_REL, __HIP_MEMORY_SCOPE_AGENT);
    while (__hip_atomic_load(&cnt[b], __ATOMIC_ACQUIRE, __HIP_MEMORY_SCOPE_AGENT) < 128) {
      __builtin_amdgcn_s_sleep(2);
    }
  }
  __syncthreads();

  // ---- stats: one lane per group, broadcast via LDS (aliases dead ci_s) ----
  float* gmu = (float*)smem;
  float* grs = (float*)(smem + 128);
  if (tid < 32) {
    float s = __hip_atomic_load(&part[(b * 32 + tid) * 2], __ATOMIC_RELAXED,
                                __HIP_MEMORY_SCOPE_AGENT);
    float ss = __hip_atomic_load(&part[(b * 32 + tid) * 2 + 1], __ATOMIC_RELAXED,
                                 __HIP_MEMORY_SCOPE_AGENT);
    float mu = s * (1.f / 32768.f);
    float var = ss * (1.f / 32768.f) - mu * mu;
    gmu[tid] = mu;
    grs[tid] = rsqrtf(var + 1e-5f);
  }
  __syncthreads();

  // ---- apply GN + ReLU from registers; single out store ----
#pragma unroll
  for (int im = 0; im < 2; im++) {
    int grp = wm * 4 + im * 2 + (lane >> 5);
    float mu = gmu[grp], rs = grs[grp];
#pragma unroll
    for (int r = 0; r < 4; r++) {
      int m = wm * 32 + im * 16 + pq * 4 + r;
      float ga = gamma[m] * rs;
      float be = beta[m] - mu * ga;
#pragma unroll
      for (int sb = 0; sb < 2; sb++) {
        int n = p0 + sb * 16 + col;
        out[(b * 256 + m) * HW + n] = fmaxf(acc[sb][im][r] * ga + be, 0.f);
      }
    }
  }
}

extern "C" void kernel_launch(void* const* d_in, const int* in_sizes, int n_in,
                              void* d_out, int out_size, void* d_ws, size_t ws_size,
                              hipStream_t stream) {
  const float* x = (const float*)d_in[0];
  const float* offset_w = (const float*)d_in[1];
  const float* offset_b = (const float*)d_in[2];
  const float* deform_w = (const float*)d_in[3];
  const float* gn_gamma = (const float*)d_in[4];
  const float* gn_beta = (const float*)d_in[5];
  float* out = (float*)d_out;
  char* ws = (char*)d_ws;

  u16* xt = (u16*)ws;                      //  8,388,608 B (bf16 NHWC)
  u16* warr = (u16*)(ws + 8388608);        //  1,179,648 B
  u16* owm = (u16*)(ws + 9568256);         //    147,456 B
  float* part = (float*)(ws + 9715712);    //      1,024 B + 16 B join counters
  int* cnt = (int*)(ws + 9715712 + 1024);

  k_pre<<<dim3(1024), dim3(256), 0, stream>>>(x, deform_w, offset_w, xt, warr, owm, part);
  k_conv<<<dim3(512), dim3(512), 0, stream>>>(xt, warr, owm, offset_b, gn_gamma,
                                              gn_beta, out, part, cnt);
}

// Round 10
// 194.612 us; speedup vs baseline: 1.1062x; 1.1062x over previous
//
#include <hip/hip_runtime.h>
#include <hip/hip_bf16.h>
#include <stdint.h>

// DeformableBlock: fused [offset-conv (MFMA) + meta + deformable conv (MFMA GEMM)]
// -> GroupNorm+ReLU.  B=4, CIN=COUT=256, H=W=64, 3x3, GN groups=32.
// Round 19: 4 barrier-groups/CU. Evidence: time tracks independent barrier
// domains per CU (1 dom: 96us; 2 dom: 75-85us regardless of waves/dom).
// k_conv -> 1024 blocks x 256 thr (4 waves, N=16, M=64/wave), LDS 22 KB
// -> 4 blocks/CU co-resident. Same MFMA count / gather traffic / schedule
// (9 taps, 1 barrier/tap, prefetch never crosses a barrier). R18's spin-join
// reverted (cost 64us to save 8).

typedef unsigned short u16;
typedef __bf16 bf16x8 __attribute__((ext_vector_type(8)));
typedef float f32x4_t __attribute__((ext_vector_type(4)));

#define HW 4096

__device__ __forceinline__ uint32_t f32_to_bf16_rne(float f) {
  uint32_t u = __builtin_bit_cast(uint32_t, f);
  return (u + 0x7FFFu + ((u >> 16) & 1u)) >> 16;
}
__device__ __forceinline__ float bf_lo(uint32_t u) {
  return __builtin_bit_cast(float, u << 16);
}
__device__ __forceinline__ float bf_hi(uint32_t u) {
  return __builtin_bit_cast(float, u & 0xFFFF0000u);
}
__device__ __forceinline__ uint32_t blend2(uint32_t a, uint32_t b, uint32_t c,
                                           uint32_t d, float4 mw) {
  float lo = mw.x * bf_lo(a) + mw.y * bf_lo(b) + mw.z * bf_lo(c) + mw.w * bf_lo(d);
  float hi = mw.x * bf_hi(a) + mw.y * bf_hi(b) + mw.z * bf_hi(c) + mw.w * bf_hi(d);
  return f32_to_bf16_rne(lo) | (f32_to_bf16_rne(hi) << 16);
}

// ---------------- Kernel PRE: transpose (64ch x 64px tiles) + weight prep ----------------
// 1024 blocks x 256 thr (R17, measured-equivalent). Block 0 zeroes part.
__global__ __launch_bounds__(256) void k_pre(const float* __restrict__ x,
                                             const float* __restrict__ wsrc,
                                             const float* __restrict__ ow,
                                             u16* __restrict__ xt,
                                             u16* __restrict__ warr,
                                             u16* __restrict__ owm,
                                             float* __restrict__ part) {
  __shared__ float tile[64][65];  // 16,640 B
  int bid = blockIdx.x;
  int tid = threadIdx.x;
  int bz = bid >> 8;
  int c0 = ((bid >> 6) & 3) * 64;
  int p0 = (bid & 63) * 64;

  {
    int ch = tid >> 4;
    int q4 = (tid & 15) * 4;
#pragma unroll
    for (int r = 0; r < 4; r++) {
      int c = r * 16 + ch;
      float4 v = *(const float4*)&x[((size_t)(bz * 256 + c0 + c)) * HW + p0 + q4];
      tile[c][q4 + 0] = v.x;
      tile[c][q4 + 1] = v.y;
      tile[c][q4 + 2] = v.z;
      tile[c][q4 + 3] = v.w;
    }
  }
  __syncthreads();
  {
    int chunk = tid & 7;
    int pxr = tid >> 3;
#pragma unroll
    for (int it = 0; it < 2; it++) {
      int px = it * 32 + pxr;
      int cb = chunk * 8;
      uint4 u;
      u.x = f32_to_bf16_rne(tile[cb + 0][px]) | (f32_to_bf16_rne(tile[cb + 1][px]) << 16);
      u.y = f32_to_bf16_rne(tile[cb + 2][px]) | (f32_to_bf16_rne(tile[cb + 3][px]) << 16);
      u.z = f32_to_bf16_rne(tile[cb + 4][px]) | (f32_to_bf16_rne(tile[cb + 5][px]) << 16);
      u.w = f32_to_bf16_rne(tile[cb + 6][px]) | (f32_to_bf16_rne(tile[cb + 7][px]) << 16);
      *(uint4*)&xt[((size_t)(bz * HW + p0 + px)) * 256 + c0 + cb] = u;
    }
  }

#pragma unroll
  for (int k = 0; k < 3; k++) {
    int i = k * 256 + tid;
    if (i < 576) {
      int e = bid * 576 + i;
      int kk = e & 7, m = (e >> 3) & 255, g = (e >> 11) & 7, kc = e >> 14;
      int cin = (kc & 3) * 64 + g * 8 + kk;
      warr[e] = (u16)f32_to_bf16_rne(wsrc[m * 2304 + cin * 9 + (kc >> 2)]);
    }
  }
  if (tid < 72) {
    int e = bid * 72 + tid;
    int kk = e & 7, m = (e >> 3) & 31, g = (e >> 8) & 7, kc = e >> 11;
    int cin = (kc & 3) * 64 + g * 8 + kk;
    float v = (m < 18) ? ow[m * 2304 + cin * 9 + (kc >> 2)] : 0.f;
    owm[e] = (u16)f32_to_bf16_rne(v);
  }
  if (bid == 0 && tid < 256) part[tid] = 0.f;
}

// ---------------- Kernel C: FUSED offset-conv + meta + deformable GEMM + GN partials ----------------
// Block = (b, 16-px tile), 1024 blocks x 256 threads (4 waves, M=64/wave, N=16).
// LDS 22 KB -> 4 blocks/CU (4 independent barrier domains).
// Phase A: offset conv M=32,N=16,K=2304 (4 waves split taps, wave-private staging).
// Meta (144 = 9 taps x 16 px) -> LDS. Phase B: 9 taps, 1 barrier/tap, per-tap
// prefetch (loads never cross a barrier), 32 MFMA/wave/tap.
__global__ __launch_bounds__(256, 4) void k_conv(
    const u16* __restrict__ xt, const u16* __restrict__ warr,
    const u16* __restrict__ owm, const float* __restrict__ ob,
    float* __restrict__ out, float* __restrict__ part) {
  __shared__ char smem[22016];
  u16* stage = (u16*)smem;                   // phase A: [w4][1088 u16]  (8704 B)
  float* off_part = (float*)(smem + 8704);   // phase A: [w4][px16][20]  (5120 B)
  int4* ci_s = (int4*)smem;                  // meta/B:  [144]           (2304 B)
  float4* mw_s = (float4*)(smem + 2304);     // meta/B:  [144]           (2304 B)
  u16* b_s = (u16*)(smem + 4608);            // phase B: [2buf][2set][16oct][136 u16] (17408 B)

  int tid = threadIdx.x;
  int lane = tid & 63;
  int wm = tid >> 6;  // 0..3
  // XCD-aware bijective swizzle (1024 blocks, 8 XCDs): each XCD gets 128
  // consecutive work-ids = 32 consecutive rows of one image (~2.2 MB + warr).
  int wk = (blockIdx.x & 7) * 128 + (blockIdx.x >> 3);
  int b = wk >> 8;
  int pt = wk & 255;   // 16-px tile index within image
  int p0 = pt * 16;
  int yrow = p0 >> 6, xbase = p0 & 63;

  // ---- Phase A: offset conv; wave w handles taps w, w+4, w+8 ----
  {
    u16* st = stage + wm * 1088;
    int q = lane & 15, pq = lane >> 4;
    int oct = lane & 7, pxs = lane >> 3;
    f32x4_t a2[2] = {};  // [im], M=32
#pragma unroll 1
    for (int tap = wm; tap < 9; tap += 4) {
      int ky = tap / 3, kx = tap % 3;
      int yy = yrow + ky - 1;
      bool vy = (yy >= 0) && (yy < 64);
#pragma unroll
      for (int cc = 0; cc < 4; cc++) {
        int kc = tap * 4 + cc;
#pragma unroll
        for (int i = 0; i < 2; i++) {
          int px = i * 8 + pxs;
          int xx2 = xbase + px + kx - 1;
          uint4 v = make_uint4(0u, 0u, 0u, 0u);
          if (vy && xx2 >= 0 && xx2 < 64)
            v = *(const uint4*)&xt[(b * HW + yy * 64 + xx2) * 256 + cc * 64 + oct * 8];
          *(uint4*)&st[oct * 136 + px * 8] = v;
        }
#pragma unroll
        for (int ks = 0; ks < 2; ks++) {
          int g = ks * 4 + pq;
          const u16* ab = owm + kc * 2048 + g * 256;
          bf16x8 bfr = *(bf16x8*)&st[g * 136 + q * 8];
#pragma unroll
          for (int im = 0; im < 2; im++) {
            bf16x8 af = *(const bf16x8*)&ab[(im * 16 + q) * 8];
            a2[im] = __builtin_amdgcn_mfma_f32_16x16x32_bf16(af, bfr, a2[im], 0, 0, 0);
          }
        }
      }
    }
    // D: col = q (px), row = pq*4+r (+im*16) = oc
#pragma unroll
    for (int im = 0; im < 2; im++)
#pragma unroll
      for (int r = 0; r < 4; r++) {
        int oc = im * 16 + pq * 4 + r;
        if (oc < 18) off_part[(wm * 16 + q) * 20 + oc] = a2[im][r];
      }
  }
  __syncthreads();
  // ---- meta: 144 = 9 taps x 16 px; results to LDS (aliases dead stage) ----
  if (tid < 144) {
    int tap = tid >> 4;
    int px = tid & 15;
    float dy = ob[2 * tap], dx = ob[2 * tap + 1];
#pragma unroll
    for (int wv = 0; wv < 4; wv++) {
      dy += off_part[(wv * 16 + px) * 20 + 2 * tap];
      dx += off_part[(wv * 16 + px) * 20 + 2 * tap + 1];
    }
    int ky = tap / 3, kx = tap % 3;
    int p = p0 + px;
    int yq = p >> 6, xq = p & 63;
    float py = (float)(yq - 1 + ky) + dy;
    float pxx = (float)(xq - 1 + kx) + dx;
    float y0f = floorf(py), x0f = floorf(pxx);
    float ty = py - y0f, tx = pxx - x0f;
    int y0 = (int)y0f, x0 = (int)x0f;
    int y1 = y0 + 1, x1 = x0 + 1;
    float wy0 = 1.f - ty, wy1 = ty, wx0 = 1.f - tx, wx1 = tx;
    bool vy0 = (y0 >= 0) && (y0 < 64), vy1 = (y1 >= 0) && (y1 < 64);
    bool vx0 = (x0 >= 0) && (x0 < 64), vx1 = (x1 >= 0) && (x1 < 64);
    int cy0 = min(max(y0, 0), 63), cy1 = min(max(y1, 0), 63);
    int cx0 = min(max(x0, 0), 63), cx1 = min(max(x1, 0), 63);
    int base = b * HW;
    int4 ci;
    ci.x = (base + cy0 * 64 + cx0) * 256;
    ci.y = (base + cy0 * 64 + cx1) * 256;
    ci.z = (base + cy1 * 64 + cx0) * 256;
    ci.w = (base + cy1 * 64 + cx1) * 256;
    float4 mw;
    mw.x = wy0 * wx0 * ((vy0 && vx0) ? 1.f : 0.f);
    mw.y = wy0 * wx1 * ((vy0 && vx1) ? 1.f : 0.f);
    mw.z = wy1 * wx0 * ((vy1 && vx0) ? 1.f : 0.f);
    mw.w = wy1 * wx1 * ((vy1 && vx1) ? 1.f : 0.f);
    ci_s[tid] = ci;
    mw_s[tid] = mw;
  }
  __syncthreads();

  // ---- Phase B: deformable GEMM M=256 (64/wave), N=16; 9 taps, 1 barrier/tap ----
  int col = lane & 15;
  int pq = lane >> 4;
  {
    int oct8 = tid & 15;   // channel octet within a 128-ch set
    int pxg = tid >> 4;    // pixel 0..15
    int e0 = oct8 * 8;
    f32x4_t acc[4] = {};   // [im], M=64/wave

    // prologue: gather tap 0, both 128-ch sets
    int4 ci = ci_s[pxg];
    float4 mw = mw_s[pxg];
    uint4 A0 = *(const uint4*)&xt[ci.x + e0];
    uint4 A1 = *(const uint4*)&xt[ci.y + e0];
    uint4 A2 = *(const uint4*)&xt[ci.z + e0];
    uint4 A3 = *(const uint4*)&xt[ci.w + e0];
    uint4 G0 = *(const uint4*)&xt[ci.x + 128 + e0];
    uint4 G1 = *(const uint4*)&xt[ci.y + 128 + e0];
    uint4 G2 = *(const uint4*)&xt[ci.z + 128 + e0];
    uint4 G3 = *(const uint4*)&xt[ci.w + 128 + e0];

#pragma unroll 1
    for (int dp = 0; dp < 9; dp++) {
      u16* bb = b_s + (dp & 1) * 4352;  // u16 units: per buf = 2 sets x 2176
      {
        uint4 u;
        u.x = blend2(A0.x, A1.x, A2.x, A3.x, mw);
        u.y = blend2(A0.y, A1.y, A2.y, A3.y, mw);
        u.z = blend2(A0.z, A1.z, A2.z, A3.z, mw);
        u.w = blend2(A0.w, A1.w, A2.w, A3.w, mw);
        *(uint4*)&bb[oct8 * 136 + pxg * 8] = u;
      }
      {
        uint4 v;
        v.x = blend2(G0.x, G1.x, G2.x, G3.x, mw);
        v.y = blend2(G0.y, G1.y, G2.y, G3.y, mw);
        v.z = blend2(G0.z, G1.z, G2.z, G3.z, mw);
        v.w = blend2(G0.w, G1.w, G2.w, G3.w, mw);
        *(uint4*)&bb[2176 + oct8 * 136 + pxg * 8] = v;
      }
      __syncthreads();  // all gathers already consumed -> vmcnt drain is free
      // prefetch tap dp+1 (consumed before the NEXT barrier: never crosses one)
      if (dp < 8) {
        ci = ci_s[(dp + 1) * 16 + pxg];
        float4 mwn = mw_s[(dp + 1) * 16 + pxg];
        A0 = *(const uint4*)&xt[ci.x + e0];
        A1 = *(const uint4*)&xt[ci.y + e0];
        A2 = *(const uint4*)&xt[ci.z + e0];
        A3 = *(const uint4*)&xt[ci.w + e0];
        G0 = *(const uint4*)&xt[ci.x + 128 + e0];
        G1 = *(const uint4*)&xt[ci.y + 128 + e0];
        G2 = *(const uint4*)&xt[ci.z + 128 + e0];
        G3 = *(const uint4*)&xt[ci.w + 128 + e0];
        mw = mwn;
      }
      // GEMM over the full tap: 8 K-steps x 4 im = 32 MFMA per wave
      __builtin_amdgcn_s_setprio(1);
#pragma unroll
      for (int ks = 0; ks < 8; ks++) {
        int set = ks >> 2;
        int ro = (ks & 3) * 4 + pq;
        bf16x8 bbv = *(const bf16x8*)&bb[set * 2176 + ro * 136 + col * 8];
        int kc = dp * 4 + (ks >> 1);
        int gg = (ks & 1) * 4 + pq;
        const u16* ab = warr + kc * 16384 + gg * 2048 + (wm * 64 + col) * 8;
#pragma unroll
        for (int im = 0; im < 4; im++) {
          bf16x8 af = *(const bf16x8*)&ab[im * 128];
          acc[im] = __builtin_amdgcn_mfma_f32_16x16x32_bf16(af, bbv, acc[im], 0, 0, 0);
        }
      }
      __builtin_amdgcn_s_setprio(0);
      // no trailing barrier: next dp writes the other buffer (2-deep rotation safe)
    }

    // epilogue: D col=px, row=pq*4+r (+im*16) -> NCHW; fused GN partial sums
#pragma unroll
    for (int im = 0; im < 4; im++) {
      float s = 0.f, ss = 0.f;
      int n = p0 + col;
#pragma unroll
      for (int r = 0; r < 4; r++) {
        int m = wm * 64 + im * 16 + pq * 4 + r;
        float v = acc[im][r];
        out[(b * 256 + m) * HW + n] = v;
        s += v;
        ss += v * v;
      }
      // this thread's 4 values share one GN group; groups split at lane 32
#pragma unroll
      for (int msk = 1; msk <= 16; msk <<= 1) {
        s += __shfl_xor(s, msk);
        ss += __shfl_xor(ss, msk);
      }
      if ((lane & 31) == 0) {
        int grp = wm * 8 + im * 2 + (lane >> 5);
        float* pp = part + (b * 32 + grp) * 2;
        atomicAdd(pp, s);
        atomicAdd(pp + 1, ss);
      }
    }
  }
}

// ---------------- Kernel N: finalize stats + normalize + ReLU in place ----------------
// 2048 blocks x 256 thr, 2 float4/thread (R17, measured-equivalent).
__global__ __launch_bounds__(256) void k_gn_apply(float* __restrict__ out,
                                                  const float2* __restrict__ part,
                                                  const float* __restrict__ gamma,
                                                  const float* __restrict__ beta) {
  int base = blockIdx.x * 512 + threadIdx.x;
#pragma unroll
  for (int k = 0; k < 2; k++) {
    int gid = base + k * 256;  // float4 index, < 1048576
    int c = (gid >> 10) & 255;
    int bb = gid >> 18;
    float2 p = part[bb * 32 + (c >> 3)];  // broadcast load
    float mu = p.x / 32768.f;
    float var = p.y / 32768.f - mu * mu;
    float rs = rsqrtf(var + 1e-5f);
    float ga = gamma[c] * rs;
    float be = beta[c] - mu * ga;
    float4 v = ((const float4*)out)[gid];
    v.x = fmaxf(v.x * ga + be, 0.f);
    v.y = fmaxf(v.y * ga + be, 0.f);
    v.z = fmaxf(v.z * ga + be, 0.f);
    v.w = fmaxf(v.w * ga + be, 0.f);
    ((float4*)out)[gid] = v;
  }
}

extern "C" void kernel_launch(void* const* d_in, const int* in_sizes, int n_in,
                              void* d_out, int out_size, void* d_ws, size_t ws_size,
                              hipStream_t stream) {
  const float* x = (const float*)d_in[0];
  const float* offset_w = (const float*)d_in[1];
  const float* offset_b = (const float*)d_in[2];
  const float* deform_w = (const float*)d_in[3];
  const float* gn_gamma = (const float*)d_in[4];
  const float* gn_beta = (const float*)d_in[5];
  float* out = (float*)d_out;
  char* ws = (char*)d_ws;

  u16* xt = (u16*)ws;                      //  8,388,608 B (bf16 NHWC)
  u16* warr = (u16*)(ws + 8388608);        //  1,179,648 B
  u16* owm = (u16*)(ws + 9568256);         //    147,456 B
  float* part = (float*)(ws + 9715712);    //      1,024 B (4b x 32g x {s,ss})

  k_pre<<<dim3(1024), dim3(256), 0, stream>>>(x, deform_w, offset_w, xt, warr, owm, part);
  k_conv<<<dim3(1024), dim3(256), 0, stream>>>(xt, warr, owm, offset_b, out, part);
  k_gn_apply<<<dim3(2048), dim3(256), 0, stream>>>(out, (const float2*)part, gn_gamma, gn_beta);
}

// Round 13
// 155.831 us; speedup vs baseline: 1.3815x; 1.2489x over previous
//
#include <hip/hip_runtime.h>
#include <hip/hip_bf16.h>
#include <stdint.h>

// DeformableBlock: fused [offset-conv (MFMA) + meta + deformable conv (MFMA GEMM)]
// -> GroupNorm+ReLU.  B=4, CIN=COUT=256, H=W=64, 3x3, GN groups=32.
// Round 22: resubmission of the best-measured build (R15 structure, passed at
// 153.8 us in Round 6). R20/R21 bench failures were infrastructure: container
// failed on byte-identical previously-passing source (no coop launch, no spin,
// no new sync; part re-zeroed by k_pre each replay -> graph-capture safe).
// Session evidence summary:
//  - k_conv plateau ~75 us: insensitive to occupancy (R10), L2 traffic (R11),
//    barrier count (R15), barrier-free (R12), decoupling (R13), prefetch window
//    (R14), barrier domains (R19). Gather->blend->LDS->MFMA chain latency floor.
//  - non-conv residue ~79 us: fixed per-dispatch pipeline cost; 4x small-kernel
//    rework null (R17); fusion via coop launch kills container (R16); spin-join
//    costs 64 us to save 8 (R18).
// Structure: k_pre (transpose+prep) -> k_conv (offset conv + meta + per-tap
// staged GEMM, 2 barrier domains/CU, XCD swizzle, setprio, fused GN partials)
// -> k_gn_apply (stats broadcast, normalize+ReLU).

typedef unsigned short u16;
typedef __bf16 bf16x8 __attribute__((ext_vector_type(8)));
typedef float f32x4_t __attribute__((ext_vector_type(4)));

#define HW 4096

__device__ __forceinline__ uint32_t f32_to_bf16_rne(float f) {
  uint32_t u = __builtin_bit_cast(uint32_t, f);
  return (u + 0x7FFFu + ((u >> 16) & 1u)) >> 16;
}
__device__ __forceinline__ float bf_lo(uint32_t u) {
  return __builtin_bit_cast(float, u << 16);
}
__device__ __forceinline__ float bf_hi(uint32_t u) {
  return __builtin_bit_cast(float, u & 0xFFFF0000u);
}
__device__ __forceinline__ uint32_t blend2(uint32_t a, uint32_t b, uint32_t c,
                                           uint32_t d, float4 mw) {
  float lo = mw.x * bf_lo(a) + mw.y * bf_lo(b) + mw.z * bf_lo(c) + mw.w * bf_lo(d);
  float hi = mw.x * bf_hi(a) + mw.y * bf_hi(b) + mw.z * bf_hi(c) + mw.w * bf_hi(d);
  return f32_to_bf16_rne(lo) | (f32_to_bf16_rne(hi) << 16);
}

// ---------------- Kernel PRE: transpose + weight prep + zero part (merged) ----------------
__global__ __launch_bounds__(256) void k_pre(const float* __restrict__ x,
                                             const float* __restrict__ wsrc,
                                             const float* __restrict__ ow,
                                             u16* __restrict__ xt,
                                             u16* __restrict__ warr,
                                             u16* __restrict__ owm,
                                             float* __restrict__ part) {
  __shared__ float tile[32][33];
  int bid = blockIdx.x;
  int tid = threadIdx.x;
  if (bid < 4096) {
    int bx = bid & 127, by = (bid >> 7) & 7, bz = bid >> 10;
    int c0 = by * 32, p0 = bx * 32;
    int tx = tid & 31, ty = tid >> 5;  // 32 x 8
#pragma unroll
    for (int j = 0; j < 32; j += 8)
      tile[ty + j][tx] = x[(bz * 256 + c0 + ty + j) * HW + p0 + tx];
    __syncthreads();
    int cp = tid & 15;
    int pr = tid >> 4;
#pragma unroll
    for (int j = 0; j < 2; j++) {
      int p = pr + j * 16;
      uint32_t lo = f32_to_bf16_rne(tile[cp * 2][p]);
      uint32_t hi = f32_to_bf16_rne(tile[cp * 2 + 1][p]);
      *(uint32_t*)&xt[(bz * HW + p0 + p) * 256 + c0 + cp * 2] = lo | (hi << 16);
    }
  } else if (bid < 6400) {
    int e = (bid - 4096) * 256 + tid;  // < 589824
    int kk = e & 7, m = (e >> 3) & 255, g = (e >> 11) & 7, kc = e >> 14;
    int cin = (kc & 3) * 64 + g * 8 + kk;
    int tap = kc >> 2;
    warr[e] = (u16)f32_to_bf16_rne(wsrc[m * 2304 + cin * 9 + tap]);
  } else if (bid < 6688) {
    int e = (bid - 6400) * 256 + tid;  // < 73728
    int kk = e & 7, m = (e >> 3) & 31, g = (e >> 8) & 7, kc = e >> 11;
    int cin = (kc & 3) * 64 + g * 8 + kk;
    int tap = kc >> 2;
    float v = (m < 18) ? ow[m * 2304 + cin * 9 + tap] : 0.f;
    owm[e] = (u16)f32_to_bf16_rne(v);
  } else {
    part[tid] = 0.f;  // 4 b * 32 groups * {s,ss} = 256 floats
  }
}

// ---------------- Kernel C: FUSED offset-conv + meta + deformable GEMM + GN partials ----------------
// Block = (b, 32-px tile), 512 blocks x 512 threads (8 waves, M=32/wave).
// Phase A: offset conv M=32,N=32,K=2304 (8 waves split 36 kc-chunks, wave-private
// LDS staging, zero barriers). Meta -> LDS.
// Phase B: 9 taps; per tap: stage 256 ch (2 sets) -> 1 barrier -> prefetch both
// sets for tap+1 -> 32-MFMA cluster (setprio). No load crosses a barrier.
__global__ __launch_bounds__(512, 4) void k_conv(
    const u16* __restrict__ xt, const u16* __restrict__ warr,
    const u16* __restrict__ owm, const float* __restrict__ ob,
    float* __restrict__ out, float* __restrict__ part) {
  __shared__ char smem[54272];
  u16* stage = (u16*)smem;                   // phase A: [w8][2112 u16] (33792 B)
  float* off_part = (float*)(smem + 33792);  // phase A: [w8][px32][20]  (20480 B)
  int4* ci_s = (int4*)smem;                  // meta/B:  [288]           (4608 B)
  float4* mw_s = (float4*)(smem + 4608);     // meta/B:  [288]           (4608 B)
  u16* b_s = (u16*)(smem + 9216);            // phase B: [2buf][2set][2sub][16oct][136 u16] (34816 B)

  int tid = threadIdx.x;
  int lane = tid & 63;
  int wm = tid >> 6;  // 0..7
  // XCD-aware bijective swizzle (512 blocks, 8 XCDs): each XCD gets 64
  // consecutive work-ids (L2 working set ~2.4 MB incl. warr).
  int wk = (blockIdx.x & 7) * 64 + (blockIdx.x >> 3);
  int b = wk >> 7;
  int pt = wk & 127;
  int p0 = pt * 32;
  int yrow = p0 >> 6, xbase = p0 & 63;

  // ---- Phase A: offset conv; wave w handles kc-chunks w, w+8, w+16, ... ----
  {
    u16* st = stage + wm * 2112;
    int q = lane & 15, pq = lane >> 4;
    int oct = lane & 7, pxs = lane >> 3;  // staging map (uint4 loads)
    f32x4_t a2[2][2] = {};
#pragma unroll 1
    for (int kc = wm; kc < 36; kc += 8) {
      int tap = kc >> 2, cc = kc & 3;
      int ky = tap / 3, kx = tap % 3;
      int yy = yrow + ky - 1;
      bool vy = (yy >= 0) && (yy < 64);
#pragma unroll
      for (int i = 0; i < 4; i++) {
        int px = i * 8 + pxs;
        int xx2 = xbase + px + kx - 1;
        uint4 v = make_uint4(0u, 0u, 0u, 0u);
        if (vy && xx2 >= 0 && xx2 < 64)
          v = *(const uint4*)&xt[(b * HW + yy * 64 + xx2) * 256 + cc * 64 + oct * 8];
        *(uint4*)&st[oct * 264 + px * 8] = v;
      }
#pragma unroll
      for (int ks = 0; ks < 2; ks++) {
        int g = ks * 4 + pq;
        const u16* ab = owm + kc * 2048 + g * 256;
#pragma unroll
        for (int s = 0; s < 2; s++) {
          bf16x8 bfr = *(bf16x8*)&st[g * 264 + (s * 16 + q) * 8];
#pragma unroll
          for (int im = 0; im < 2; im++) {
            bf16x8 af = *(const bf16x8*)&ab[(im * 16 + q) * 8];
            a2[s][im] = __builtin_amdgcn_mfma_f32_16x16x32_bf16(af, bfr, a2[s][im], 0, 0, 0);
          }
        }
      }
    }
#pragma unroll
    for (int s = 0; s < 2; s++)
#pragma unroll
      for (int im = 0; im < 2; im++)
#pragma unroll
        for (int r = 0; r < 4; r++) {
          int oc = im * 16 + pq * 4 + r;
          if (oc < 18) off_part[(wm * 32 + s * 16 + q) * 20 + oc] = a2[s][im][r];
        }
  }
  __syncthreads();
  // ---- meta: 288 = 9 taps x 32 px; results to LDS (aliases dead stage) ----
  for (int it = tid; it < 288; it += 512) {
    int tap = it >> 5;
    int px = it & 31;
    float dy = ob[2 * tap], dx = ob[2 * tap + 1];
#pragma unroll
    for (int wv = 0; wv < 8; wv++) {
      dy += off_part[(wv * 32 + px) * 20 + 2 * tap];
      dx += off_part[(wv * 32 + px) * 20 + 2 * tap + 1];
    }
    int ky = tap / 3, kx = tap % 3;
    int p = p0 + px;
    int yq = p >> 6, xq = p & 63;
    float py = (float)(yq - 1 + ky) + dy;
    float pxx = (float)(xq - 1 + kx) + dx;
    float y0f = floorf(py), x0f = floorf(pxx);
    float ty = py - y0f, tx = pxx - x0f;
    int y0 = (int)y0f, x0 = (int)x0f;
    int y1 = y0 + 1, x1 = x0 + 1;
    float wy0 = 1.f - ty, wy1 = ty, wx0 = 1.f - tx, wx1 = tx;
    bool vy0 = (y0 >= 0) && (y0 < 64), vy1 = (y1 >= 0) && (y1 < 64);
    bool vx0 = (x0 >= 0) && (x0 < 64), vx1 = (x1 >= 0) && (x1 < 64);
    int cy0 = min(max(y0, 0), 63), cy1 = min(max(y1, 0), 63);
    int cx0 = min(max(x0, 0), 63), cx1 = min(max(x1, 0), 63);
    int base = b * HW;
    int4 ci;
    ci.x = (base + cy0 * 64 + cx0) * 256;
    ci.y = (base + cy0 * 64 + cx1) * 256;
    ci.z = (base + cy1 * 64 + cx0) * 256;
    ci.w = (base + cy1 * 64 + cx1) * 256;
    float4 mw;
    mw.x = wy0 * wx0 * ((vy0 && vx0) ? 1.f : 0.f);
    mw.y = wy0 * wx1 * ((vy0 && vx1) ? 1.f : 0.f);
    mw.z = wy1 * wx0 * ((vy1 && vx0) ? 1.f : 0.f);
    mw.w = wy1 * wx1 * ((vy1 && vx1) ? 1.f : 0.f);
    ci_s[it] = ci;
    mw_s[it] = mw;
  }
  __syncthreads();

  // ---- Phase B: deformable GEMM M=256, N=32; 9 taps, 1 barrier/tap ----
  {
    int oct8 = tid & 15;   // channel octet within a 128-ch set
    int pxg = tid >> 4;    // pixel 0..31 (this thread's staging pixel)
    int sub = pxg >> 4;    // subtile of the staged pixel
    int pxw = pxg & 15;
    int col = lane & 15;
    int pq = lane >> 4;
    int e0 = oct8 * 8;
    f32x4_t acc[2][2] = {};  // [sub][im]

    // prologue: gather tap 0, both 128-ch sets
    int4 ci = ci_s[pxg];
    float4 mw = mw_s[pxg];
    uint4 A0 = *(const uint4*)&xt[ci.x + e0];
    uint4 A1 = *(const uint4*)&xt[ci.y + e0];
    uint4 A2 = *(const uint4*)&xt[ci.z + e0];
    uint4 A3 = *(const uint4*)&xt[ci.w + e0];
    uint4 G0 = *(const uint4*)&xt[ci.x + 128 + e0];
    uint4 G1 = *(const uint4*)&xt[ci.y + 128 + e0];
    uint4 G2 = *(const uint4*)&xt[ci.z + 128 + e0];
    uint4 G3 = *(const uint4*)&xt[ci.w + 128 + e0];

#pragma unroll 1
    for (int dp = 0; dp < 9; dp++) {
      u16* bb = b_s + (dp & 1) * 8704;
      // stage full tap: set 0 (ch 0-127) + set 1 (ch 128-255)
      {
        uint4 u;
        u.x = blend2(A0.x, A1.x, A2.x, A3.x, mw);
        u.y = blend2(A0.y, A1.y, A2.y, A3.y, mw);
        u.z = blend2(A0.z, A1.z, A2.z, A3.z, mw);
        u.w = blend2(A0.w, A1.w, A2.w, A3.w, mw);
        *(uint4*)&bb[sub * 2176 + oct8 * 136 + pxw * 8] = u;
      }
      {
        uint4 v;
        v.x = blend2(G0.x, G1.x, G2.x, G3.x, mw);
        v.y = blend2(G0.y, G1.y, G2.y, G3.y, mw);
        v.z = blend2(G0.z, G1.z, G2.z, G3.z, mw);
        v.w = blend2(G0.w, G1.w, G2.w, G3.w, mw);
        *(uint4*)&bb[4352 + sub * 2176 + oct8 * 136 + pxw * 8] = v;
      }
      __syncthreads();  // all gathers already consumed -> vmcnt drain is free
      // prefetch tap dp+1 (issued here, consumed before the NEXT barrier:
      // these loads never cross a barrier)
      if (dp < 8) {
        ci = ci_s[(dp + 1) * 32 + pxg];
        float4 mwn = mw_s[(dp + 1) * 32 + pxg];
        A0 = *(const uint4*)&xt[ci.x + e0];
        A1 = *(const uint4*)&xt[ci.y + e0];
        A2 = *(const uint4*)&xt[ci.z + e0];
        A3 = *(const uint4*)&xt[ci.w + e0];
        G0 = *(const uint4*)&xt[ci.x + 128 + e0];
        G1 = *(const uint4*)&xt[ci.y + 128 + e0];
        G2 = *(const uint4*)&xt[ci.z + 128 + e0];
        G3 = *(const uint4*)&xt[ci.w + 128 + e0];
        mw = mwn;
      }
      // GEMM over the full tap: 8 K-steps, 32 MFMA per wave
      __builtin_amdgcn_s_setprio(1);
#pragma unroll
      for (int ks = 0; ks < 8; ks++) {
        int set = ks >> 2;
        int ro = (ks & 3) * 4 + pq;
        const u16* bp = bb + set * 4352 + ro * 136 + col * 8;
        bf16x8 bb0 = *(const bf16x8*)&bp[0];
        bf16x8 bb1 = *(const bf16x8*)&bp[2176];
        int kc = dp * 4 + (ks >> 1);
        int gg = (ks & 1) * 4 + pq;
        const u16* ab = warr + kc * 16384 + gg * 2048 + (wm * 32 + col) * 8;
#pragma unroll
        for (int im = 0; im < 2; im++) {
          bf16x8 af = *(const bf16x8*)&ab[im * 128];
          acc[0][im] = __builtin_amdgcn_mfma_f32_16x16x32_bf16(af, bb0, acc[0][im], 0, 0, 0);
          acc[1][im] = __builtin_amdgcn_mfma_f32_16x16x32_bf16(af, bb1, acc[1][im], 0, 0, 0);
        }
      }
      __builtin_amdgcn_s_setprio(0);
      // no trailing barrier: next dp writes the other buffer (2-deep rotation safe)
    }

    // epilogue: D col=px-in-sub, row=pq*4+r -> NCHW; fused GN partial sums
#pragma unroll
    for (int im = 0; im < 2; im++) {
      float s = 0.f, ss = 0.f;
#pragma unroll
      for (int sb = 0; sb < 2; sb++) {
        int n = p0 + sb * 16 + col;
#pragma unroll
        for (int r = 0; r < 4; r++) {
          int m = wm * 32 + im * 16 + pq * 4 + r;
          float v = acc[sb][im][r];
          out[(b * 256 + m) * HW + n] = v;
          s += v;
          ss += v * v;
        }
      }
#pragma unroll
      for (int msk = 1; msk <= 16; msk <<= 1) {
        s += __shfl_xor(s, msk);
        ss += __shfl_xor(ss, msk);
      }
      if ((lane & 31) == 0) {
        int grp = wm * 4 + im * 2 + (lane >> 5);
        float* pp = part + (b * 32 + grp) * 2;
        atomicAdd(pp, s);
        atomicAdd(pp + 1, ss);
      }
    }
  }
}

// ---------------- Kernel N: finalize stats + normalize + ReLU in place ----------------
__global__ __launch_bounds__(256) void k_gn_apply(float* __restrict__ out,
                                                  const float2* __restrict__ part,
                                                  const float* __restrict__ gamma,
                                                  const float* __restrict__ beta) {
  int gid = blockIdx.x * 256 + threadIdx.x;  // float4 index, < 1048576
  int c = (gid >> 10) & 255;
  int bb = gid >> 18;
  float2 p = part[bb * 32 + (c >> 3)];  // broadcast load (same addr across block)
  float mu = p.x / 32768.f;
  float var = p.y / 32768.f - mu * mu;
  float rs = rsqrtf(var + 1e-5f);
  float ga = gamma[c] * rs;
  float be = beta[c] - mu * ga;
  float4 v = ((const float4*)out)[gid];
  v.x = fmaxf(v.x * ga + be, 0.f);
  v.y = fmaxf(v.y * ga + be, 0.f);
  v.z = fmaxf(v.z * ga + be, 0.f);
  v.w = fmaxf(v.w * ga + be, 0.f);
  ((float4*)out)[gid] = v;
}

extern "C" void kernel_launch(void* const* d_in, const int* in_sizes, int n_in,
                              void* d_out, int out_size, void* d_ws, size_t ws_size,
                              hipStream_t stream) {
  const float* x = (const float*)d_in[0];
  const float* offset_w = (const float*)d_in[1];
  const float* offset_b = (const float*)d_in[2];
  const float* deform_w = (const float*)d_in[3];
  const float* gn_gamma = (const float*)d_in[4];
  const float* gn_beta = (const float*)d_in[5];
  float* out = (float*)d_out;
  char* ws = (char*)d_ws;

  u16* xt = (u16*)ws;                      //  8,388,608 B (bf16 NHWC)
  u16* warr = (u16*)(ws + 8388608);        //  1,179,648 B
  u16* owm = (u16*)(ws + 9568256);         //    147,456 B
  float* part = (float*)(ws + 9715712);    //      1,024 B (4b x 32g x {s,ss})

  k_pre<<<dim3(6689), dim3(256), 0, stream>>>(x, deform_w, offset_w, xt, warr, owm, part);
  k_conv<<<dim3(512), dim3(512), 0, stream>>>(xt, warr, owm, offset_b, out, part);
  k_gn_apply<<<dim3(4096), dim3(256), 0, stream>>>(out, (const float2*)part, gn_gamma, gn_beta);
}